// Round 9
// baseline (119.936 us; speedup 1.0000x reference)
//
#include <hip/hip_runtime.h>
#include <cmath>

#define IMG_H 512
#define IMG_W 512
#define TH 32            // tile rows (output)
#define TW 64            // tile cols (output)
#define NCOL 80          // stored cols per row (64 + 2*8 halo)
#define PL 80            // plane stride within a row (dwords)
#define ROWSTRIDE 402    // row stride (dwords): even (b64 align), ==18 mod 32 -> 2-way max bank spread
#define NPLANES 96       // 32 batch * 3 channels
#define NPIX 25165824.0  // 96*512*512

typedef float vf2 __attribute__((ext_vector_type(2)));

struct GaussW { float w[11]; };

__global__ __launch_bounds__(256, 3) void ssim_main(
    const float* __restrict__ img1, const float* __restrict__ img2,
    float* __restrict__ partials, GaussW gw, int use_atomic, float* __restrict__ out)
{
    // Plane-major row layout: L[r][plane][col], planes A,B,P,Q,S.
    // Phase-1 writes natural column-pair b64; phase-2 forms (A,B)/(P,Q) pairs
    // via ds_read2_b32 (offset0:k, offset1:80+k) -> aligned VGPR pairs, 0 VALU.
    __shared__ float L[TH * ROWSTRIDE];   // 51456 B -> 3 blocks/CU
    __shared__ float wsum[4];

    const int tid = threadIdx.x;
    const int plane = blockIdx.z;
    const int tr0 = blockIdx.y * TH;
    const int tc0 = blockIdx.x * TW;
    const float* __restrict__ plane1 = img1 + ((size_t)plane << 18);  // uniform SGPR base
    const float* __restrict__ plane2 = img2 + ((size_t)plane << 18);

    // Hoist the 11 weight pairs into VGPRs once (kills per-use {wt,wt} movs).
    vf2 wv[11];
    #pragma unroll
    for (int t = 0; t < 11; ++t) { wv[t].x = gw.w[t]; wv[t].y = gw.w[t]; }
    #pragma unroll
    for (int t = 0; t < 11; ++t) asm("" : "+v"(wv[t]));

    // ---------------- Phase 1: vertical conv on adjacent-column pairs --------
    // 160 active threads: pair index p -> cols (2p, 2p+1); 4 chunks x 8 rows.
    // global_load_dwordx2 delivers aligned (col,col+1) pairs directly; since
    // gc is even, a pair is always entirely in or out of range -> scalar mask.
    // Single code path (round-4 scratch lesson), first-touch accumulator init.
    {
        const int p = tid % 40;       // column-pair index
        const int chunk = tid / 40;   // 0..3 active
        if (chunk < 4) {
            const int r0 = chunk * 8;
            const int gc = tc0 + 2 * p - 8;               // even
            const bool cok = (unsigned)gc < IMG_W;        // whole pair in/out
            const int gcc = min(max(gc, 0), IMG_W - 2);

            vf2 aA[8], aB[8], aP[8], aQ[8], aS[8];

            #pragma unroll
            for (int ii = 0; ii < 18; ++ii) {             // input rows r0-5 .. r0+12
                const int gr = tr0 + r0 - 5 + ii;
                const float m = ((unsigned)gr < IMG_H) & cok ? 1.f : 0.f;
                const int grc = min(max(gr, 0), IMG_H - 1);
                const uint32_t off = (uint32_t)(grc * IMG_W + gcc);
                vf2 a2 = *(const vf2*)(plane1 + off);     // global_load_dwordx2
                vf2 b2 = *(const vf2*)(plane2 + off);
                a2.x *= m; a2.y *= m; b2.x *= m; b2.y *= m;
                const vf2 p2 = a2 * a2;                   // v_pk_mul_f32
                const vf2 q2 = b2 * b2;
                const vf2 s2 = a2 * b2;
                #pragma unroll
                for (int o = 0; o < 8; ++o) {
                    if (o <= ii && ii <= o + 10) {        // compile-time predicate
                        const vf2 w2 = wv[ii - o];
                        if (ii == o) {                    // first touch
                            aA[o] = w2 * a2; aB[o] = w2 * b2; aP[o] = w2 * p2;
                            aQ[o] = w2 * q2; aS[o] = w2 * s2;
                        } else {
                            aA[o] = __builtin_elementwise_fma(w2, a2, aA[o]);
                            aB[o] = __builtin_elementwise_fma(w2, b2, aB[o]);
                            aP[o] = __builtin_elementwise_fma(w2, p2, aP[o]);
                            aQ[o] = __builtin_elementwise_fma(w2, q2, aQ[o]);
                            aS[o] = __builtin_elementwise_fma(w2, s2, aS[o]);
                        }
                    }
                }
            }
            const int j = 2 * p;
            #pragma unroll
            for (int o = 0; o < 8; ++o) {
                float* row = &L[(r0 + o) * ROWSTRIDE];
                *(vf2*)&row[j]          = aA[o];          // ds_write_b64, natural pairs
                *(vf2*)&row[PL + j]     = aB[o];
                *(vf2*)&row[2 * PL + j] = aP[o];
                *(vf2*)&row[3 * PL + j] = aQ[o];
                *(vf2*)&row[4 * PL + j] = aS[o];
            }
        }
    }
    __syncthreads();

    // ---------------- Phase 2: horizontal conv, packed per-column scatter -----
    // Row index in LOW lane bits (402r = 18r mod 32, gcd 2 -> 2-way max, free).
    // (A,B) and (P,Q) pairs formed by ds_read2_b32; scatter into pk accumulators.
    float lsum = 0.f;
    {
        const int r = tid & 31;        // 0..31  (low bits!)
        const int c0 = (tid >> 5) * 8; // col group 0..7
        const float* row  = &L[r * ROWSTRIDE + c0];
        const float* row2 = row + 2 * PL;

        vf2 mAB[8], ePQ[8];
        float e12[8];

        #pragma unroll
        for (int k = 3; k <= 20; ++k) {          // window cols c0+3 .. c0+20
            vf2 vab, vpq;
            vab.x = row[k];  vab.y = row[PL + k];      // ds_read2_b32 k / 80+k
            vpq.x = row2[k]; vpq.y = row2[PL + k];     // ds_read2_b32
            const float vs = row2[2 * PL + k];         // ds_read_b32 160+k
            #pragma unroll
            for (int c = 0; c < 8; ++c) {
                if (k - 13 <= c && c <= k - 3) {            // compile-time
                    const vf2 w2 = wv[k - 3 - c];
                    const float wt = gw.w[k - 3 - c];
                    if (k == c + 3) {                        // first touch
                        mAB[c] = w2 * vab;
                        ePQ[c] = w2 * vpq;
                        e12[c] = wt * vs;
                    } else {
                        mAB[c] = __builtin_elementwise_fma(w2, vab, mAB[c]);
                        ePQ[c] = __builtin_elementwise_fma(w2, vpq, ePQ[c]);
                        e12[c] = fmaf(wt, vs, e12[c]);
                    }
                }
            }
        }
        #pragma unroll
        for (int c = 0; c < 8; ++c) {
            const float a1 = mAB[c].x, a2 = mAB[c].y;
            const float den1 = fmaf(a1, a1, fmaf(a2, a2, 0.0001f)); // mu11+mu22+C1
            const float s11  = fmaf(-a1, a1, ePQ[c].x);
            const float s22  = fmaf(-a2, a2, ePQ[c].y);
            const float s12  = fmaf(-a1, a2, e12[c]);
            const float mu12 = a1 * a2;
            const float num  = fmaf(2.f, mu12, 0.0001f) * fmaf(2.f, s12, 0.0009f);
            const float den  = den1 * (s11 + s22 + 0.0009f);
            lsum = fmaf(num, __builtin_amdgcn_rcpf(den), lsum);     // rcp ~1ulp, tol 2.7e-4
        }
    }
    // block reduction
    #pragma unroll
    for (int off = 32; off; off >>= 1) lsum += __shfl_down(lsum, off, 64);
    if ((tid & 63) == 0) wsum[tid >> 6] = lsum;
    __syncthreads();
    if (tid == 0) {
        const float bs = wsum[0] + wsum[1] + wsum[2] + wsum[3];
        if (use_atomic) {
            atomicAdd(out, bs * (float)(1.0 / NPIX));
        } else {
            const int bId = (blockIdx.z * gridDim.y + blockIdx.y) * gridDim.x + blockIdx.x;
            partials[bId] = bs;
        }
    }
}

__global__ __launch_bounds__(256) void ssim_reduce(
    const float* __restrict__ partials, int n, float* __restrict__ out)
{
    const int tid = threadIdx.x;
    double s = 0.0;
    for (int i = tid; i < n; i += 256) s += (double)partials[i];
    #pragma unroll
    for (int off = 32; off; off >>= 1) s += __shfl_down(s, off, 64);
    __shared__ double ws[4];
    if ((tid & 63) == 0) ws[tid >> 6] = s;
    __syncthreads();
    if (tid == 0) out[0] = (float)(((ws[0] + ws[1]) + (ws[2] + ws[3])) / NPIX);
}

extern "C" void kernel_launch(void* const* d_in, const int* in_sizes, int n_in,
                              void* d_out, int out_size, void* d_ws, size_t ws_size,
                              hipStream_t stream) {
    const float* img1 = (const float*)d_in[0];
    const float* img2 = (const float*)d_in[1];
    float* out = (float*)d_out;

    // Gaussian window (host, double precision, normalized)
    GaussW gw;
    {
        double g[11], sum = 0.0;
        for (int i = 0; i < 11; ++i) {
            const double c = (double)(i - 5);
            g[i] = std::exp(-(c * c) / 4.5);   // 2*sigma^2 = 4.5
            sum += g[i];
        }
        for (int i = 0; i < 11; ++i) gw.w[i] = (float)(g[i] / sum);
    }

    dim3 grid(IMG_W / TW, IMG_H / TH, NPLANES);   // 8 x 16 x 96 = 12288
    const int nPart = grid.x * grid.y * grid.z;

    if (ws_size >= (size_t)nPart * sizeof(float)) {
        // deterministic two-stage reduction
        ssim_main<<<grid, 256, 0, stream>>>(img1, img2, (float*)d_ws, gw, 0, out);
        ssim_reduce<<<1, 256, 0, stream>>>((float*)d_ws, nPart, out);
    } else {
        // fallback: atomic accumulation (still within tolerance)
        hipMemsetAsync(d_out, 0, sizeof(float), stream);
        ssim_main<<<grid, 256, 0, stream>>>(img1, img2, nullptr, gw, 1, out);
    }
}

// Round 10
// 110.319 us; speedup vs baseline: 1.0872x; 1.0872x over previous
//
#include <hip/hip_runtime.h>
#include <cmath>

#define IMG_H 512
#define IMG_W 512
#define TH 32            // tile rows (round-6 best base)
#define TW 64            // tile cols
#define LDSW 83          // ODD element stride -- load-bearing (round 9: even stride = 4-way b32 conflicts)
#define NPLANES 96       // 32 batch * 3 channels
#define NPIX 25165824.0  // 96*512*512

typedef float vf2 __attribute__((ext_vector_type(2)));

struct GaussW { float w[11]; };

__global__ __launch_bounds__(256, 3) void ssim_main(
    const float* __restrict__ img1, const float* __restrict__ img2,
    float* __restrict__ partials, GaussW gw, int use_atomic, float* __restrict__ out)
{
    // Interleaved pair layout: (A,B) and (P,Q) share weights -> v_pk_fma_f32.
    __shared__ vf2   VAB[TH][LDSW];   // 21248 B
    __shared__ vf2   VPQ[TH][LDSW];   // 21248 B
    __shared__ float VS [TH][LDSW];   // 10624 B   (total ~53 KB -> 3 blocks/CU)
    __shared__ float wsum[4];

    const int tid = threadIdx.x;
    const int plane = blockIdx.z;
    const int tr0 = blockIdx.y * TH;
    const int tc0 = blockIdx.x * TW;
    const float* __restrict__ plane1 = img1 + ((size_t)plane << 18);  // uniform -> SGPR base
    const float* __restrict__ plane2 = img2 + ((size_t)plane << 18);

    // ---------------- Phase 1: vertical conv, packed accumulator scatter ------
    // 240 threads: one lds column j each, 11 output rows (chunk r0 = {0,11,22}).
    // Block-uniform interior/border split with FULLY SELF-CONTAINED arms
    // (round-4 scratch came from arms sharing accumulators + tail across the
    // join; here the only cross-arm state is LDS).
    {
        const int j = tid % 80;       // lds col
        const int chunk = tid / 80;   // 0..2 active; tid>=240 idle
        if (chunk < 3) {
            const int r0 = chunk * 11;
            const int gc = tc0 + j - 8;
            const bool interior = (blockIdx.x >= 1) & (blockIdx.x <= 6)
                                & (blockIdx.y >= 1) & (blockIdx.y <= 14);
            if (interior) {
                // ---- interior arm: no clamps, no masks, incremental offset ----
                vf2 aAB[11], aPQ[11];
                float aS[11];
                uint32_t off = (uint32_t)((tr0 + r0 - 5) * IMG_W + gc);
                #pragma unroll
                for (int ii = 0; ii < 21; ++ii) {
                    const float a = plane1[off];
                    const float b = plane2[off];
                    off += IMG_W;                       // 1 VALU/row
                    const vf2 ab = { a, b };
                    const vf2 pq = ab * ab;             // v_pk_mul_f32
                    const float s = a * b;
                    #pragma unroll
                    for (int o = 0; o < 11; ++o) {
                        if (o <= ii && ii <= o + 10) {  // compile-time predicate
                            const float wt = gw.w[ii - o];
                            const vf2 wtv = { wt, wt };
                            if (ii == o) {              // first touch
                                aAB[o] = wtv * ab;
                                aPQ[o] = wtv * pq;
                                aS[o]  = wt * s;
                            } else {
                                aAB[o] = __builtin_elementwise_fma(wtv, ab, aAB[o]);
                                aPQ[o] = __builtin_elementwise_fma(wtv, pq, aPQ[o]);
                                aS[o]  = fmaf(wt, s, aS[o]);
                            }
                        }
                    }
                }
                #pragma unroll
                for (int o = 0; o < 11; ++o) {
                    const int r = r0 + o;
                    if (r0 + o < TH) {                  // only chunk2/o=10 false
                        VAB[r][j] = aAB[o];             // ds_write_b64
                        VPQ[r][j] = aPQ[o];
                        VS [r][j] = aS[o];
                    }
                }
            } else {
                // ---- border arm: round-6 body verbatim (clamp + zero-mask) ----
                vf2 aAB[11], aPQ[11];
                float aS[11];
                const float cmask = ((unsigned)gc < IMG_W) ? 1.f : 0.f;
                const int gcc = min(max(gc, 0), IMG_W - 1);   // v_med3
                #pragma unroll
                for (int ii = 0; ii < 21; ++ii) {
                    const int gr = tr0 + r0 - 5 + ii;
                    const float rmask = ((unsigned)gr < IMG_H) ? cmask : 0.f;
                    const int grc = min(max(gr, 0), IMG_H - 1);
                    const uint32_t idx = (uint32_t)(grc * IMG_W + gcc);
                    const float a = plane1[idx] * rmask;
                    const float b = plane2[idx] * rmask;
                    const vf2 ab = { a, b };
                    const vf2 pq = ab * ab;
                    const float s = a * b;
                    #pragma unroll
                    for (int o = 0; o < 11; ++o) {
                        if (o <= ii && ii <= o + 10) {
                            const float wt = gw.w[ii - o];
                            const vf2 wtv = { wt, wt };
                            if (ii == o) {
                                aAB[o] = wtv * ab;
                                aPQ[o] = wtv * pq;
                                aS[o]  = wt * s;
                            } else {
                                aAB[o] = __builtin_elementwise_fma(wtv, ab, aAB[o]);
                                aPQ[o] = __builtin_elementwise_fma(wtv, pq, aPQ[o]);
                                aS[o]  = fmaf(wt, s, aS[o]);
                            }
                        }
                    }
                }
                #pragma unroll
                for (int o = 0; o < 11; ++o) {
                    const int r = r0 + o;
                    if (r0 + o < TH) {
                        VAB[r][j] = aAB[o];
                        VPQ[r][j] = aPQ[o];
                        VS [r][j] = aS[o];
                    }
                }
            }
        }
    }
    __syncthreads();

    // ---------------- Phase 2: horizontal conv, packed per-column scatter -----
    // Row index in LOW lane bits (round-6 bank fix): b64 pair (83r+8cg+k) mod 16
    // covers all 16 pairs x2 per half-wave; b32 covers all 32 banks x2 -> free.
    float lsum = 0.f;
    {
        const int r = tid & 31;        // 0..31  (low bits!)
        const int c0 = (tid >> 5) * 8; // col group 0..7
        const vf2*   __restrict__ bAB = &VAB[r][c0];
        const vf2*   __restrict__ bPQ = &VPQ[r][c0];
        const float* __restrict__ bS  = &VS [r][c0];

        vf2 mAB[8], ePQ[8];
        float e12[8];

        #pragma unroll
        for (int k = 3; k <= 20; ++k) {          // window cols c0+3 .. c0+20
            const vf2   vab = bAB[k];
            const vf2   vpq = bPQ[k];
            const float vs  = bS[k];
            #pragma unroll
            for (int c = 0; c < 8; ++c) {
                if (k - 13 <= c && c <= k - 3) {            // compile-time
                    const float wt = gw.w[k - 3 - c];
                    const vf2 wtv = { wt, wt };
                    if (k == c + 3) {                        // first touch
                        mAB[c] = wtv * vab;
                        ePQ[c] = wtv * vpq;
                        e12[c] = wt * vs;
                    } else {
                        mAB[c] = __builtin_elementwise_fma(wtv, vab, mAB[c]);
                        ePQ[c] = __builtin_elementwise_fma(wtv, vpq, ePQ[c]);
                        e12[c] = fmaf(wt, vs, e12[c]);
                    }
                }
            }
        }
        #pragma unroll
        for (int c = 0; c < 8; ++c) {
            const float a1 = mAB[c].x, a2 = mAB[c].y;
            const float den1 = fmaf(a1, a1, fmaf(a2, a2, 0.0001f)); // mu11+mu22+C1
            const float s11  = fmaf(-a1, a1, ePQ[c].x);
            const float s22  = fmaf(-a2, a2, ePQ[c].y);
            const float s12  = fmaf(-a1, a2, e12[c]);
            const float mu12 = a1 * a2;
            const float num  = fmaf(2.f, mu12, 0.0001f) * fmaf(2.f, s12, 0.0009f);
            const float den  = den1 * (s11 + s22 + 0.0009f);
            lsum = fmaf(num, __builtin_amdgcn_rcpf(den), lsum);     // rcp ~1ulp, tol 2.7e-4
        }
    }
    // block reduction
    #pragma unroll
    for (int off = 32; off; off >>= 1) lsum += __shfl_down(lsum, off, 64);
    if ((tid & 63) == 0) wsum[tid >> 6] = lsum;
    __syncthreads();
    if (tid == 0) {
        const float bs = wsum[0] + wsum[1] + wsum[2] + wsum[3];
        if (use_atomic) {
            atomicAdd(out, bs * (float)(1.0 / NPIX));
        } else {
            const int bId = (blockIdx.z * gridDim.y + blockIdx.y) * gridDim.x + blockIdx.x;
            partials[bId] = bs;
        }
    }
}

__global__ __launch_bounds__(256) void ssim_reduce(
    const float* __restrict__ partials, int n, float* __restrict__ out)
{
    const int tid = threadIdx.x;
    double s = 0.0;
    for (int i = tid; i < n; i += 256) s += (double)partials[i];
    #pragma unroll
    for (int off = 32; off; off >>= 1) s += __shfl_down(s, off, 64);
    __shared__ double ws[4];
    if ((tid & 63) == 0) ws[tid >> 6] = s;
    __syncthreads();
    if (tid == 0) out[0] = (float)(((ws[0] + ws[1]) + (ws[2] + ws[3])) / NPIX);
}

extern "C" void kernel_launch(void* const* d_in, const int* in_sizes, int n_in,
                              void* d_out, int out_size, void* d_ws, size_t ws_size,
                              hipStream_t stream) {
    const float* img1 = (const float*)d_in[0];
    const float* img2 = (const float*)d_in[1];
    float* out = (float*)d_out;

    // Gaussian window (host, double precision, normalized)
    GaussW gw;
    {
        double g[11], sum = 0.0;
        for (int i = 0; i < 11; ++i) {
            const double c = (double)(i - 5);
            g[i] = std::exp(-(c * c) / 4.5);   // 2*sigma^2 = 4.5
            sum += g[i];
        }
        for (int i = 0; i < 11; ++i) gw.w[i] = (float)(g[i] / sum);
    }

    dim3 grid(IMG_W / TW, IMG_H / TH, NPLANES);   // 8 x 16 x 96 = 12288
    const int nPart = grid.x * grid.y * grid.z;

    if (ws_size >= (size_t)nPart * sizeof(float)) {
        // deterministic two-stage reduction
        ssim_main<<<grid, 256, 0, stream>>>(img1, img2, (float*)d_ws, gw, 0, out);
        ssim_reduce<<<1, 256, 0, stream>>>((float*)d_ws, nPart, out);
    } else {
        // fallback: atomic accumulation (still within tolerance)
        hipMemsetAsync(d_out, 0, sizeof(float), stream);
        ssim_main<<<grid, 256, 0, stream>>>(img1, img2, nullptr, gw, 1, out);
    }
}

// Round 11
// 97.502 us; speedup vs baseline: 1.2301x; 1.1314x over previous
//
#include <hip/hip_runtime.h>
#include <cmath>

#define IMG_H 512
#define IMG_W 512
#define TH 32            // tile rows (round-6 proven base)
#define TW 64            // tile cols
#define LDSW 83          // ODD element stride -- load-bearing (even => 4-way b32 / 16-way b64 conflicts)
#define NPLANES 96       // 32 batch * 3 channels
#define NPIX 25165824.0  // 96*512*512

typedef float vf2 __attribute__((ext_vector_type(2)));

struct GaussW { float w[11]; };

// ALGEBRAIC MERGE: sigma1_sq and sigma2_sq only appear as their SUM in SSIM:
//   den = (mu1^2+mu2^2+C1) * ((conv(a^2+b^2) - mu1^2 - mu2^2) + C2)
// so we convolve T = a^2+b^2 instead of P,Q separately -> 4 arrays = 2 vf2
// pairs (A,B),(T,S); every tap is exactly 2 v_pk_fma_f32 (was 2 pk + 1 fma).
__global__ __launch_bounds__(256, 3) void ssim_main(
    const float* __restrict__ img1, const float* __restrict__ img2,
    float* __restrict__ partials, GaussW gw, int use_atomic, float* __restrict__ out)
{
    __shared__ vf2 VAB[TH][LDSW];   // 21248 B
    __shared__ vf2 VTS[TH][LDSW];   // 21248 B  (total ~42.5 KB -> 3 blocks/CU)
    __shared__ float wsum[4];

    const int tid = threadIdx.x;
    const int plane = blockIdx.z;
    const int tr0 = blockIdx.y * TH;
    const int tc0 = blockIdx.x * TW;
    const float* __restrict__ plane1 = img1 + ((size_t)plane << 18);  // uniform -> SGPR base
    const float* __restrict__ plane2 = img2 + ((size_t)plane << 18);

    // ---------------- Phase 1: vertical conv, packed accumulator scatter ------
    // 240 threads: one lds column j each, 11 output rows (chunk r0 = {0,11,22}).
    // Single code path (round-4 scratch lesson), first-touch init.
    {
        const int j = tid % 80;       // lds col
        const int chunk = tid / 80;   // 0..2 active; tid>=240 idle
        if (chunk < 3) {
            const int r0 = chunk * 11;
            const int gc = tc0 + j - 8;
            const float cmask = ((unsigned)gc < IMG_W) ? 1.f : 0.f;
            const int gcc = min(max(gc, 0), IMG_W - 1);   // v_med3

            vf2 aAB[11], aTS[11];

            #pragma unroll
            for (int ii = 0; ii < 21; ++ii) {
                const int gr = tr0 + r0 - 5 + ii;
                const float rmask = ((unsigned)gr < IMG_H) ? cmask : 0.f;
                const int grc = min(max(gr, 0), IMG_H - 1);
                const uint32_t idx = (uint32_t)(grc * IMG_W + gcc);
                const float a = plane1[idx] * rmask;
                const float b = plane2[idx] * rmask;
                const vf2 ab = { a, b };
                const vf2 pq = ab * ab;                    // v_pk_mul_f32
                const vf2 ts = { pq.x + pq.y, a * b };     // (a^2+b^2, a*b)
                #pragma unroll
                for (int o = 0; o < 11; ++o) {
                    if (o <= ii && ii <= o + 10) {          // compile-time predicate
                        const float wt = gw.w[ii - o];
                        const vf2 wtv = { wt, wt };
                        if (ii == o) {                       // first touch
                            aAB[o] = wtv * ab;
                            aTS[o] = wtv * ts;
                        } else {
                            aAB[o] = __builtin_elementwise_fma(wtv, ab, aAB[o]);
                            aTS[o] = __builtin_elementwise_fma(wtv, ts, aTS[o]);
                        }
                    }
                }
            }
            #pragma unroll
            for (int o = 0; o < 11; ++o) {
                const int r = r0 + o;
                if (r0 + o < TH) {   // only chunk2/o=10 is false
                    VAB[r][j] = aAB[o];        // ds_write_b64
                    VTS[r][j] = aTS[o];        // ds_write_b64
                }
            }
        }
    }
    __syncthreads();

    // ---------------- Phase 2: horizontal conv, packed per-column scatter -----
    // Row index in LOW lane bits (round-6 bank fix): b64 pair (83r+8cg+k) mod 16
    // covers all 16 pairs x2 per half-wave -> hardware minimum, conflict-free.
    float lsum = 0.f;
    {
        const int r = tid & 31;        // 0..31  (low bits!)
        const int c0 = (tid >> 5) * 8; // col group 0..7
        const vf2* __restrict__ bAB = &VAB[r][c0];
        const vf2* __restrict__ bTS = &VTS[r][c0];

        vf2 mAB[8], eTS[8];

        #pragma unroll
        for (int k = 3; k <= 20; ++k) {          // window cols c0+3 .. c0+20
            const vf2 vab = bAB[k];              // ds_read_b64, immediate offset
            const vf2 vts = bTS[k];              // ds_read_b64
            #pragma unroll
            for (int c = 0; c < 8; ++c) {
                if (k - 13 <= c && c <= k - 3) {            // compile-time
                    const float wt = gw.w[k - 3 - c];
                    const vf2 wtv = { wt, wt };
                    if (k == c + 3) {                        // first touch
                        mAB[c] = wtv * vab;
                        eTS[c] = wtv * vts;
                    } else {
                        mAB[c] = __builtin_elementwise_fma(wtv, vab, mAB[c]);
                        eTS[c] = __builtin_elementwise_fma(wtv, vts, eTS[c]);
                    }
                }
            }
        }
        #pragma unroll
        for (int c = 0; c < 8; ++c) {
            const float a1 = mAB[c].x, a2 = mAB[c].y;   // mu1, mu2
            const float T  = eTS[c].x, S = eTS[c].y;    // conv(a^2+b^2), conv(ab)
            const float h    = fmaf(a1, a1, a2 * a2);   // mu11 + mu22
            const float mu12 = a1 * a2;
            const float num  = fmaf(2.f, mu12, 0.0001f)
                             * fmaf(2.f, S - mu12, 0.0009f);   // (2mu12+C1)(2s12+C2)
            const float den  = (h + 0.0001f) * ((T - h) + 0.0009f);
            lsum = fmaf(num, __builtin_amdgcn_rcpf(den), lsum); // rcp ~1ulp, tol 2.7e-4
        }
    }
    // block reduction
    #pragma unroll
    for (int off = 32; off; off >>= 1) lsum += __shfl_down(lsum, off, 64);
    if ((tid & 63) == 0) wsum[tid >> 6] = lsum;
    __syncthreads();
    if (tid == 0) {
        const float bs = wsum[0] + wsum[1] + wsum[2] + wsum[3];
        if (use_atomic) {
            atomicAdd(out, bs * (float)(1.0 / NPIX));
        } else {
            const int bId = (blockIdx.z * gridDim.y + blockIdx.y) * gridDim.x + blockIdx.x;
            partials[bId] = bs;
        }
    }
}

__global__ __launch_bounds__(256) void ssim_reduce(
    const float* __restrict__ partials, int n, float* __restrict__ out)
{
    const int tid = threadIdx.x;
    double s = 0.0;
    for (int i = tid; i < n; i += 256) s += (double)partials[i];
    #pragma unroll
    for (int off = 32; off; off >>= 1) s += __shfl_down(s, off, 64);
    __shared__ double ws[4];
    if ((tid & 63) == 0) ws[tid >> 6] = s;
    __syncthreads();
    if (tid == 0) out[0] = (float)(((ws[0] + ws[1]) + (ws[2] + ws[3])) / NPIX);
}

extern "C" void kernel_launch(void* const* d_in, const int* in_sizes, int n_in,
                              void* d_out, int out_size, void* d_ws, size_t ws_size,
                              hipStream_t stream) {
    const float* img1 = (const float*)d_in[0];
    const float* img2 = (const float*)d_in[1];
    float* out = (float*)d_out;

    // Gaussian window (host, double precision, normalized)
    GaussW gw;
    {
        double g[11], sum = 0.0;
        for (int i = 0; i < 11; ++i) {
            const double c = (double)(i - 5);
            g[i] = std::exp(-(c * c) / 4.5);   // 2*sigma^2 = 4.5
            sum += g[i];
        }
        for (int i = 0; i < 11; ++i) gw.w[i] = (float)(g[i] / sum);
    }

    dim3 grid(IMG_W / TW, IMG_H / TH, NPLANES);   // 8 x 16 x 96 = 12288
    const int nPart = grid.x * grid.y * grid.z;

    if (ws_size >= (size_t)nPart * sizeof(float)) {
        // deterministic two-stage reduction
        ssim_main<<<grid, 256, 0, stream>>>(img1, img2, (float*)d_ws, gw, 0, out);
        ssim_reduce<<<1, 256, 0, stream>>>((float*)d_ws, nPart, out);
    } else {
        // fallback: atomic accumulation (still within tolerance)
        hipMemsetAsync(d_out, 0, sizeof(float), stream);
        ssim_main<<<grid, 256, 0, stream>>>(img1, img2, nullptr, gw, 1, out);
    }
}

// Round 12
// 92.984 us; speedup vs baseline: 1.2899x; 1.0486x over previous
//
#include <hip/hip_runtime.h>
#include <cmath>

#define IMG_H 512
#define IMG_W 512
#define TH 32            // tile rows (proven base)
#define TW 64            // tile cols
#define LDSW 75          // ODD element stride (load-bearing!); 74 used cols + 1 pad
#define NPLANES 96       // 32 batch * 3 channels
#define NPIX 25165824.0  // 96*512*512

typedef float vf2 __attribute__((ext_vector_type(2)));

struct GaussW { float w[11]; };

// 4-array algebraic form (round 11): convolve (A,B) and (T,S), T = a^2+b^2:
//   den = (mu1^2+mu2^2+C1) * ((conv(T) - mu1^2 - mu2^2) + C2)
// Round 12: store only the 74 needed halo cols (was 80) -> LDS 43->38.4 KB
// -> 4 blocks/CU (16 waves, 40% occupancy) to cut the ~41us stall term.
__global__ __launch_bounds__(256, 4) void ssim_main(
    const float* __restrict__ img1, const float* __restrict__ img2,
    float* __restrict__ partials, GaussW gw, int use_atomic, float* __restrict__ out)
{
    __shared__ vf2 VAB[TH][LDSW];   // 19200 B
    __shared__ vf2 VTS[TH][LDSW];   // 19200 B  (total 38.4 KB -> 4 blocks/CU)
    __shared__ float wsum[4];

    const int tid = threadIdx.x;
    const int plane = blockIdx.z;
    const int tr0 = blockIdx.y * TH;
    const int tc0 = blockIdx.x * TW;
    const float* __restrict__ plane1 = img1 + ((size_t)plane << 18);  // uniform -> SGPR base
    const float* __restrict__ plane2 = img2 + ((size_t)plane << 18);

    // ---------------- Phase 1: vertical conv, packed accumulator scatter ------
    // 3 chunks x 74 active threads: one lds column j (gc = tc0 + j - 5) each,
    // 11 output rows per chunk. Single code path, first-touch init.
    {
        const int j = tid % 80;       // lds col
        const int chunk = tid / 80;   // 0..2; active if chunk<3 && j<74
        if (chunk < 3 && j < 74) {
            const int r0 = chunk * 11;
            const int gc = tc0 + j - 5;
            const float cmask = ((unsigned)gc < IMG_W) ? 1.f : 0.f;
            const int gcc = min(max(gc, 0), IMG_W - 1);   // v_med3

            vf2 aAB[11], aTS[11];

            #pragma unroll
            for (int ii = 0; ii < 21; ++ii) {
                const int gr = tr0 + r0 - 5 + ii;
                const float rmask = ((unsigned)gr < IMG_H) ? cmask : 0.f;
                const int grc = min(max(gr, 0), IMG_H - 1);
                const uint32_t idx = (uint32_t)(grc * IMG_W + gcc);
                const float a = plane1[idx] * rmask;
                const float b = plane2[idx] * rmask;
                const vf2 ab = { a, b };
                const vf2 pq = ab * ab;                    // v_pk_mul_f32
                const vf2 ts = { pq.x + pq.y, a * b };     // (a^2+b^2, a*b)
                #pragma unroll
                for (int o = 0; o < 11; ++o) {
                    if (o <= ii && ii <= o + 10) {          // compile-time predicate
                        const float wt = gw.w[ii - o];
                        const vf2 wtv = { wt, wt };
                        if (ii == o) {                       // first touch
                            aAB[o] = wtv * ab;
                            aTS[o] = wtv * ts;
                        } else {
                            aAB[o] = __builtin_elementwise_fma(wtv, ab, aAB[o]);
                            aTS[o] = __builtin_elementwise_fma(wtv, ts, aTS[o]);
                        }
                    }
                }
            }
            #pragma unroll
            for (int o = 0; o < 11; ++o) {
                const int r = r0 + o;
                if (r0 + o < TH) {   // only chunk2/o=10 is false
                    VAB[r][j] = aAB[o];        // ds_write_b64
                    VTS[r][j] = aTS[o];        // ds_write_b64
                }
            }
        }
    }
    __syncthreads();

    // ---------------- Phase 2: horizontal conv, packed per-column scatter -----
    // Row index in LOW lane bits: b64 pair (75r + c0 + k) mod 16, 75 odd ->
    // all 16 pairs x2 per half-wave = hardware minimum, conflict-free.
    float lsum = 0.f;
    {
        const int r = tid & 31;        // 0..31  (low bits!)
        const int c0 = (tid >> 5) * 8; // col group 0..7
        const vf2* __restrict__ bAB = &VAB[r][c0];
        const vf2* __restrict__ bTS = &VTS[r][c0];

        vf2 mAB[8], eTS[8];

        #pragma unroll
        for (int k = 0; k <= 17; ++k) {          // stored cols c0 .. c0+17
            const vf2 vab = bAB[k];              // ds_read_b64, immediate offset
            const vf2 vts = bTS[k];              // ds_read_b64
            #pragma unroll
            for (int c = 0; c < 8; ++c) {
                if (k - 10 <= c && c <= k) {                // compile-time
                    const float wt = gw.w[k - c];
                    const vf2 wtv = { wt, wt };
                    if (k == c) {                            // first touch (tap 0)
                        mAB[c] = wtv * vab;
                        eTS[c] = wtv * vts;
                    } else {
                        mAB[c] = __builtin_elementwise_fma(wtv, vab, mAB[c]);
                        eTS[c] = __builtin_elementwise_fma(wtv, vts, eTS[c]);
                    }
                }
            }
        }
        #pragma unroll
        for (int c = 0; c < 8; ++c) {
            const float a1 = mAB[c].x, a2 = mAB[c].y;   // mu1, mu2
            const float T  = eTS[c].x, S = eTS[c].y;    // conv(a^2+b^2), conv(ab)
            const float h    = fmaf(a1, a1, a2 * a2);   // mu11 + mu22
            const float mu12 = a1 * a2;
            const float num  = fmaf(2.f, mu12, 0.0001f)
                             * fmaf(2.f, S - mu12, 0.0009f);   // (2mu12+C1)(2s12+C2)
            const float den  = (h + 0.0001f) * ((T - h) + 0.0009f);
            lsum = fmaf(num, __builtin_amdgcn_rcpf(den), lsum); // rcp ~1ulp, tol 2.7e-4
        }
    }
    // block reduction
    #pragma unroll
    for (int off = 32; off; off >>= 1) lsum += __shfl_down(lsum, off, 64);
    if ((tid & 63) == 0) wsum[tid >> 6] = lsum;
    __syncthreads();
    if (tid == 0) {
        const float bs = wsum[0] + wsum[1] + wsum[2] + wsum[3];
        if (use_atomic) {
            atomicAdd(out, bs * (float)(1.0 / NPIX));
        } else {
            const int bId = (blockIdx.z * gridDim.y + blockIdx.y) * gridDim.x + blockIdx.x;
            partials[bId] = bs;
        }
    }
}

__global__ __launch_bounds__(256) void ssim_reduce(
    const float* __restrict__ partials, int n, float* __restrict__ out)
{
    const int tid = threadIdx.x;
    double s = 0.0;
    for (int i = tid; i < n; i += 256) s += (double)partials[i];
    #pragma unroll
    for (int off = 32; off; off >>= 1) s += __shfl_down(s, off, 64);
    __shared__ double ws[4];
    if ((tid & 63) == 0) ws[tid >> 6] = s;
    __syncthreads();
    if (tid == 0) out[0] = (float)(((ws[0] + ws[1]) + (ws[2] + ws[3])) / NPIX);
}

extern "C" void kernel_launch(void* const* d_in, const int* in_sizes, int n_in,
                              void* d_out, int out_size, void* d_ws, size_t ws_size,
                              hipStream_t stream) {
    const float* img1 = (const float*)d_in[0];
    const float* img2 = (const float*)d_in[1];
    float* out = (float*)d_out;

    // Gaussian window (host, double precision, normalized)
    GaussW gw;
    {
        double g[11], sum = 0.0;
        for (int i = 0; i < 11; ++i) {
            const double c = (double)(i - 5);
            g[i] = std::exp(-(c * c) / 4.5);   // 2*sigma^2 = 4.5
            sum += g[i];
        }
        for (int i = 0; i < 11; ++i) gw.w[i] = (float)(g[i] / sum);
    }

    dim3 grid(IMG_W / TW, IMG_H / TH, NPLANES);   // 8 x 16 x 96 = 12288
    const int nPart = grid.x * grid.y * grid.z;

    if (ws_size >= (size_t)nPart * sizeof(float)) {
        // deterministic two-stage reduction
        ssim_main<<<grid, 256, 0, stream>>>(img1, img2, (float*)d_ws, gw, 0, out);
        ssim_reduce<<<1, 256, 0, stream>>>((float*)d_ws, nPart, out);
    } else {
        // fallback: atomic accumulation (still within tolerance)
        hipMemsetAsync(d_out, 0, sizeof(float), stream);
        ssim_main<<<grid, 256, 0, stream>>>(img1, img2, nullptr, gw, 1, out);
    }
}

// Round 13
// 90.689 us; speedup vs baseline: 1.3225x; 1.0253x over previous
//
#include <hip/hip_runtime.h>
#include <cmath>

#define IMG_H 512
#define IMG_W 512
#define TH 32            // tile rows (proven base)
#define TW 64            // tile cols
#define LDSW 75          // ODD element stride (load-bearing!); 74 used cols + 1 pad
#define NPLANES 96       // 32 batch * 3 channels
#define NPIX 25165824.0  // 96*512*512

typedef float vf2 __attribute__((ext_vector_type(2)));

struct GaussW { float w[11]; };

// 4-array algebraic form (round 11): convolve (A,B) and (T,S), T = a^2+b^2:
//   den = (mu1^2+mu2^2+C1) * ((conv(T) - mu1^2 - mu2^2) + C2)
// Round 13: register-stage ALL 42 phase-1 global loads before the tap loop
// (VGPR was 52 -> compiler kept a tiny load window; 76 regs sat unused under
// the 128/4-wave cap while each load batch exposed full HBM/L2 latency).
__global__ __launch_bounds__(256, 4) void ssim_main(
    const float* __restrict__ img1, const float* __restrict__ img2,
    float* __restrict__ partials, GaussW gw, int use_atomic, float* __restrict__ out)
{
    __shared__ vf2 VAB[TH][LDSW];   // 19200 B
    __shared__ vf2 VTS[TH][LDSW];   // 19200 B  (total 38.4 KB -> 4 blocks/CU)
    __shared__ float wsum[4];

    const int tid = threadIdx.x;
    const int plane = blockIdx.z;
    const int tr0 = blockIdx.y * TH;
    const int tc0 = blockIdx.x * TW;
    const float* __restrict__ plane1 = img1 + ((size_t)plane << 18);  // uniform -> SGPR base
    const float* __restrict__ plane2 = img2 + ((size_t)plane << 18);

    // ---------------- Phase 1: vertical conv, packed accumulator scatter ------
    // 3 chunks x 74 active threads: one lds column j (gc = tc0 + j - 5) each,
    // 11 output rows per chunk. Single code path, first-touch init.
    {
        const int j = tid % 80;       // lds col
        const int chunk = tid / 80;   // 0..2; active if chunk<3 && j<74
        if (chunk < 3 && j < 74) {
            const int r0 = chunk * 11;
            const int gc = tc0 + j - 5;
            const float cmask = ((unsigned)gc < IMG_W) ? 1.f : 0.f;
            const int gcc = min(max(gc, 0), IMG_W - 1);   // v_med3

            // ---- stage ALL loads first: one latency exposure, 42 in flight ----
            float ra[21], rb[21];
            #pragma unroll
            for (int ii = 0; ii < 21; ++ii) {
                const int gr = tr0 + r0 - 5 + ii;
                const int grc = min(max(gr, 0), IMG_H - 1);
                const uint32_t idx = (uint32_t)(grc * IMG_W + gcc);
                ra[ii] = plane1[idx];
                rb[ii] = plane2[idx];
            }
            __builtin_amdgcn_sched_barrier(0);   // pin load issue before tap stream

            vf2 aAB[11], aTS[11];
            #pragma unroll
            for (int ii = 0; ii < 21; ++ii) {
                const int gr = tr0 + r0 - 5 + ii;
                const float rmask = ((unsigned)gr < IMG_H) ? cmask : 0.f;
                const float a = ra[ii] * rmask;
                const float b = rb[ii] * rmask;
                const vf2 ab = { a, b };
                const vf2 pq = ab * ab;                    // v_pk_mul_f32
                const vf2 ts = { pq.x + pq.y, a * b };     // (a^2+b^2, a*b)
                #pragma unroll
                for (int o = 0; o < 11; ++o) {
                    if (o <= ii && ii <= o + 10) {          // compile-time predicate
                        const float wt = gw.w[ii - o];
                        const vf2 wtv = { wt, wt };
                        if (ii == o) {                       // first touch
                            aAB[o] = wtv * ab;
                            aTS[o] = wtv * ts;
                        } else {
                            aAB[o] = __builtin_elementwise_fma(wtv, ab, aAB[o]);
                            aTS[o] = __builtin_elementwise_fma(wtv, ts, aTS[o]);
                        }
                    }
                }
            }
            #pragma unroll
            for (int o = 0; o < 11; ++o) {
                const int r = r0 + o;
                if (r0 + o < TH) {   // only chunk2/o=10 is false
                    VAB[r][j] = aAB[o];        // ds_write_b64
                    VTS[r][j] = aTS[o];        // ds_write_b64
                }
            }
        }
    }
    __syncthreads();

    // ---------------- Phase 2: horizontal conv, packed per-column scatter -----
    // Row index in LOW lane bits: b64 pair (75r + c0 + k) mod 16, 75 odd ->
    // all 16 pairs x2 per half-wave = hardware minimum, conflict-free.
    float lsum = 0.f;
    {
        const int r = tid & 31;        // 0..31  (low bits!)
        const int c0 = (tid >> 5) * 8; // col group 0..7
        const vf2* __restrict__ bAB = &VAB[r][c0];
        const vf2* __restrict__ bTS = &VTS[r][c0];

        vf2 mAB[8], eTS[8];

        #pragma unroll
        for (int k = 0; k <= 17; ++k) {          // stored cols c0 .. c0+17
            const vf2 vab = bAB[k];              // ds_read_b64, immediate offset
            const vf2 vts = bTS[k];              // ds_read_b64
            #pragma unroll
            for (int c = 0; c < 8; ++c) {
                if (k - 10 <= c && c <= k) {                // compile-time
                    const float wt = gw.w[k - c];
                    const vf2 wtv = { wt, wt };
                    if (k == c) {                            // first touch (tap 0)
                        mAB[c] = wtv * vab;
                        eTS[c] = wtv * vts;
                    } else {
                        mAB[c] = __builtin_elementwise_fma(wtv, vab, mAB[c]);
                        eTS[c] = __builtin_elementwise_fma(wtv, vts, eTS[c]);
                    }
                }
            }
        }
        #pragma unroll
        for (int c = 0; c < 8; ++c) {
            const float a1 = mAB[c].x, a2 = mAB[c].y;   // mu1, mu2
            const float T  = eTS[c].x, S = eTS[c].y;    // conv(a^2+b^2), conv(ab)
            const float h    = fmaf(a1, a1, a2 * a2);   // mu11 + mu22
            const float mu12 = a1 * a2;
            const float num  = fmaf(2.f, mu12, 0.0001f)
                             * fmaf(2.f, S - mu12, 0.0009f);   // (2mu12+C1)(2s12+C2)
            const float den  = (h + 0.0001f) * ((T - h) + 0.0009f);
            lsum = fmaf(num, __builtin_amdgcn_rcpf(den), lsum); // rcp ~1ulp, tol 2.7e-4
        }
    }
    // block reduction
    #pragma unroll
    for (int off = 32; off; off >>= 1) lsum += __shfl_down(lsum, off, 64);
    if ((tid & 63) == 0) wsum[tid >> 6] = lsum;
    __syncthreads();
    if (tid == 0) {
        const float bs = wsum[0] + wsum[1] + wsum[2] + wsum[3];
        if (use_atomic) {
            atomicAdd(out, bs * (float)(1.0 / NPIX));
        } else {
            const int bId = (blockIdx.z * gridDim.y + blockIdx.y) * gridDim.x + blockIdx.x;
            partials[bId] = bs;
        }
    }
}

__global__ __launch_bounds__(256) void ssim_reduce(
    const float* __restrict__ partials, int n, float* __restrict__ out)
{
    const int tid = threadIdx.x;
    double s = 0.0;
    for (int i = tid; i < n; i += 256) s += (double)partials[i];
    #pragma unroll
    for (int off = 32; off; off >>= 1) s += __shfl_down(s, off, 64);
    __shared__ double ws[4];
    if ((tid & 63) == 0) ws[tid >> 6] = s;
    __syncthreads();
    if (tid == 0) out[0] = (float)(((ws[0] + ws[1]) + (ws[2] + ws[3])) / NPIX);
}

extern "C" void kernel_launch(void* const* d_in, const int* in_sizes, int n_in,
                              void* d_out, int out_size, void* d_ws, size_t ws_size,
                              hipStream_t stream) {
    const float* img1 = (const float*)d_in[0];
    const float* img2 = (const float*)d_in[1];
    float* out = (float*)d_out;

    // Gaussian window (host, double precision, normalized)
    GaussW gw;
    {
        double g[11], sum = 0.0;
        for (int i = 0; i < 11; ++i) {
            const double c = (double)(i - 5);
            g[i] = std::exp(-(c * c) / 4.5);   // 2*sigma^2 = 4.5
            sum += g[i];
        }
        for (int i = 0; i < 11; ++i) gw.w[i] = (float)(g[i] / sum);
    }

    dim3 grid(IMG_W / TW, IMG_H / TH, NPLANES);   // 8 x 16 x 96 = 12288
    const int nPart = grid.x * grid.y * grid.z;

    if (ws_size >= (size_t)nPart * sizeof(float)) {
        // deterministic two-stage reduction
        ssim_main<<<grid, 256, 0, stream>>>(img1, img2, (float*)d_ws, gw, 0, out);
        ssim_reduce<<<1, 256, 0, stream>>>((float*)d_ws, nPart, out);
    } else {
        // fallback: atomic accumulation (still within tolerance)
        hipMemsetAsync(d_out, 0, sizeof(float), stream);
        ssim_main<<<grid, 256, 0, stream>>>(img1, img2, nullptr, gw, 1, out);
    }
}